// Round 6
// baseline (215.291 us; speedup 1.0000x reference)
//
#include <hip/hip_runtime.h>
#include <hip/hip_bf16.h>
#include <math.h>

// Problem constants (B=16, L=256, D=256, K=16384)
#define NROWS 4096               // B*L anchors / z rows
#define KMEM  16384
#define NCAND 20480              // NROWS + KMEM candidates
#define DIM   256                // feature dim
#define TM    128                // anchor rows per block
#define TN    128                // candidate cols per tile
#define BK    64                 // k-depth per LDS stage (bf16)
#define NSLICE 16                // 512 blocks = 2 blocks/CU (64KB LDS)
#define COLS_PER_SLICE (NCAND / NSLICE)       // 1280
#define TILES_PER_SLICE (COLS_PER_SLICE / TN) // 10
#define INV_T  (1.0f / 0.07f)
#define SCALE2 (1.4426950408889634f / 0.07f)  // log2(e)/T
#define LN2    0.6931471805599453f
#define MERGE_STRIDE 33          // conflict-free merge: (tid*33+x)%32 distinct

typedef short  short8 __attribute__((ext_vector_type(8)));  // 8 bf16 (4 VGPRs)
typedef float  f32x4  __attribute__((ext_vector_type(4)));  // MFMA C/D
typedef unsigned short ushort_t;

// RNE float->bf16 (inputs are finite normals; no NaN path needed)
__device__ inline ushort_t f2bf(float x) {
    union { float f; unsigned u; } a; a.f = x;
    unsigned r = a.u + 0x7fff + ((a.u >> 16) & 1);
    return (ushort_t)(r >> 16);
}

// async global->LDS, 16B per lane, dest = wave-uniform base + lane*16
__device__ inline void load_lds16(const void* g, void* l) {
    __builtin_amdgcn_global_load_lds(
        (const __attribute__((address_space(1))) unsigned int*)g,
        (__attribute__((address_space(3))) unsigned int*)l, 16, 0, 0);
}

// Kernel 0: cast fp32 -> bf16 into cand = [z ; mem]; zero control words
// (grp[32] row-group counters, done, loss) for this launch.
__global__ __launch_bounds__(256) void cast_kernel(
    const float* __restrict__ z, const float* __restrict__ mem,
    ushort_t* __restrict__ cand, unsigned* __restrict__ ctrl)
{
    if (blockIdx.x == 0 && threadIdx.x < 34) ctrl[threadIdx.x] = 0u;
    const int idx = blockIdx.x * 256 + threadIdx.x;  // float4 index, < 1310720
    const int ZQ = NROWS * DIM / 4;                  // 262144
    const float4 v = (idx < ZQ) ? ((const float4*)z)[idx]
                                : ((const float4*)mem)[idx - ZQ];
    ushort4 u; u.x = f2bf(v.x); u.y = f2bf(v.y); u.z = f2bf(v.z); u.w = f2bf(v.w);
    ((ushort4*)cand)[idx] = u;
}

// Kernel A: double-buffered MFMA flash-LSE + fused finalization.
// Chunk-major LDS layout: element offset(row, chunk16B) =
//   (row>>4)*1024 + chunk*128 + (row&15)*8
// matches global_load_lds's fixed dest = base + lane*16 when lane ->
// (row = lane&15, chunk = lane>>4). Fragment ds_read_b128 addresses are then
// one precomputed VGPR + compile-time immediates (ti*1024 + ks*512): no
// per-stage address VALU, bank-uniform (2-way = free).
// Finalization: slice-0 blocks compute fp32 pos-dots in their prologue;
// the last block of each row-group (grp counter) combines that group's 128
// rows across 16 slices; the last group-finisher writes the scalar loss.
__global__ __launch_bounds__(256) void mfma_lse_kernel(
    const ushort_t* __restrict__ cand, const float* __restrict__ zf,
    float* __restrict__ part_m, float* __restrict__ part_s,
    float* __restrict__ pos, unsigned* __restrict__ ctrl,
    float* __restrict__ out)
{
    __shared__ __align__(16) ushort_t lds[4 * TM * BK];  // 64 KB: A0 A1 B0 B1
    __shared__ int sFlag;
    ushort_t* ldsA = lds;                  // [2][8192] elems
    ushort_t* ldsB = lds + 2 * TM * BK;    // [2][8192]

    const int tid  = threadIdx.x;
    const int lane = tid & 63;
    const int w    = tid >> 6;        // wave 0..3
    const int wr   = w >> 1;          // wave row half (0/1)
    const int wc   = w & 1;           // wave col half
    const int quad = lane >> 4;
    const int ln   = lane & 15;
    const int bx   = blockIdx.x;
    const int rowBase = bx * TM;
    const int slice   = blockIdx.y;
    const int colSliceBase = slice * COLS_PER_SLICE;

    unsigned* grp  = ctrl;            // [32] row-group arrival counters
    unsigned* done = ctrl + 32;       // group-finisher count
    float*    loss = (float*)(ctrl + 33);

    // Staging bases: lane -> (row = lane&15, chunk16B = lane>>4).
    // Instr (g = 2w+gg, h): global = base + g*16*DIM + kk + h*32 (elems);
    // LDS dest = buf*8192 + g*1024 + h*512 (elems).
    const ushort_t* agA = cand + (size_t)(rowBase      + ln) * DIM + quad * 8;
    const ushort_t* bgB = cand + (size_t)(colSliceBase + ln) * DIM + quad * 8;
    // NOTE: ln==lane&15, quad==lane>>4 — exactly the staging lane mapping.

    auto stage = [&](int t, int kk, int buf) {
        const ushort_t* bg = bgB + (size_t)t * (TN * DIM) + kk;
        const ushort_t* ag = agA + kk;
        ushort_t* la = ldsA + buf * (TM * BK) + (2 * w) * 1024;
        ushort_t* lb = ldsB + buf * (TM * BK) + (2 * w) * 1024;
#pragma unroll
        for (int gg = 0; gg < 2; ++gg)
#pragma unroll
            for (int h = 0; h < 2; ++h) {
                load_lds16(ag + (2 * w + gg) * (16 * DIM) + h * 32,
                           la + gg * 1024 + h * 512);
                load_lds16(bg + (2 * w + gg) * (16 * DIM) + h * 32,
                           lb + gg * 1024 + h * 512);
            }
    };

    // Fragment read bases (chunk-major): per-lane, loop-invariant.
    const int fragA = wr * 4096 + quad * 128 + ln * 8;   // + ti*1024 + ks*512
    const int fragB = wc * 4096 + quad * 128 + ln * 8;   // + tj*1024 + ks*512

    float m2[16], s[16];
#pragma unroll
    for (int i = 0; i < 16; ++i) { m2[i] = -INFINITY; s[i] = 0.0f; }

    f32x4 acc[4][4];
#pragma unroll
    for (int ti = 0; ti < 4; ++ti)
#pragma unroll
        for (int tj = 0; tj < 4; ++tj) acc[ti][tj] = (f32x4)0.0f;

    stage(0, 0, 0);        // prologue: stage 0 -> buffer 0

    // slice-0 blocks: exact fp32 positive dots for this row-group
    // (overlaps the first stage's load latency; released by grp counter).
    if (slice == 0 && tid < TM) {
        const int row = rowBase + tid;
        if ((row & 255) != 255) {       // valid pair; also guards row 4095
            const float4* a = (const float4*)(zf + (size_t)row * DIM);
            const float4* b = (const float4*)(zf + (size_t)(row + 1) * DIM);
            float dot = 0.0f;
#pragma unroll
            for (int q = 0; q < DIM / 4; ++q) {
                const float4 av = a[q], bv = b[q];
                dot += av.x * bv.x + av.y * bv.y + av.z * bv.z + av.w * bv.w;
            }
            __hip_atomic_store(pos + row, dot * INV_T,
                               __ATOMIC_RELAXED, __HIP_MEMORY_SCOPE_AGENT);
        }
    }
    __syncthreads();

    for (int t = 0; t < TILES_PER_SLICE; ++t) {
#pragma unroll
        for (int q = 0; q < 4; ++q) {
            const int buf = q & 1;
            if (q < 3)                        stage(t,     (q + 1) * BK, buf ^ 1);
            else if (t + 1 < TILES_PER_SLICE) stage(t + 1, 0,            buf ^ 1);

            const ushort_t* la = ldsA + buf * (TM * BK);
            const ushort_t* lb = ldsB + buf * (TM * BK);
#pragma unroll
            for (int ks = 0; ks < 2; ++ks) {
                short8 af[4], bfr[4];
#pragma unroll
                for (int ti = 0; ti < 4; ++ti)
                    af[ti] = *(const short8*)(la + fragA + ti * 1024 + ks * 512);
#pragma unroll
                for (int tj = 0; tj < 4; ++tj)
                    bfr[tj] = *(const short8*)(lb + fragB + tj * 1024 + ks * 512);
#pragma unroll
                for (int ti = 0; ti < 4; ++ti)
#pragma unroll
                    for (int tj = 0; tj < 4; ++tj)
                        acc[ti][tj] = __builtin_amdgcn_mfma_f32_16x16x32_bf16(
                            af[ti], bfr[tj], acc[ti][tj], 0, 0, 0);
            }

            if (q == 3) {
                // Per-tile epilogue (runs while next tile's loads fly).
                // C/D layout: col = ln+16*tj+64*wc, row = quad*4+reg+16*ti+64*wr
                const int colBase = colSliceBase + t * TN;
                const bool hasDiag =
                    (colBase < rowBase + TM) && (rowBase < colBase + TN);
#pragma unroll
                for (int ti = 0; ti < 4; ++ti) {
#pragma unroll
                    for (int r = 0; r < 4; ++r) {
                        const int idx = ti * 4 + r;
                        float v0 = acc[ti][0][r], v1 = acc[ti][1][r];
                        float v2 = acc[ti][2][r], v3 = acc[ti][3][r];
                        if (hasDiag) {
                            const int grow = rowBase + wr * 64 + ti * 16 + quad * 4 + r;
                            const int gc0  = colBase + wc * 64 + ln;
                            if (gc0      == grow) v0 = -3.0e38f;  // mask self
                            if (gc0 + 16 == grow) v1 = -3.0e38f;
                            if (gc0 + 32 == grow) v2 = -3.0e38f;
                            if (gc0 + 48 == grow) v3 = -3.0e38f;
                        }
                        const float tmax = fmaxf(fmaxf(v0, v1), fmaxf(v2, v3)) * SCALE2;
                        const float mo = m2[idx];
                        const float mn = fmaxf(mo, tmax);
                        const float sc2 = __builtin_amdgcn_exp2f(mo - mn);
                        s[idx] = s[idx] * sc2
                               + __builtin_amdgcn_exp2f(fmaf(v0, SCALE2, -mn))
                               + __builtin_amdgcn_exp2f(fmaf(v1, SCALE2, -mn))
                               + __builtin_amdgcn_exp2f(fmaf(v2, SCALE2, -mn))
                               + __builtin_amdgcn_exp2f(fmaf(v3, SCALE2, -mn));
                        m2[idx] = mn;
                        acc[ti][0][r] = 0.0f; acc[ti][1][r] = 0.0f;
                        acc[ti][2][r] = 0.0f; acc[ti][3][r] = 0.0f;
                    }
                }
            }
            __syncthreads();
        }
    }

    // Cross-lane merge: 32 partials per row (16 ln x 2 wc), stride-33 overlay.
    float* smf = (float*)lds;              // [128][33] m partials
    float* ssf = smf + TM * MERGE_STRIDE;  // [128][33] s partials
    const int p = wc * 16 + ln;
#pragma unroll
    for (int ti = 0; ti < 4; ++ti)
#pragma unroll
        for (int r = 0; r < 4; ++r) {
            const int rl = wr * 64 + ti * 16 + quad * 4 + r;
            smf[rl * MERGE_STRIDE + p] = m2[ti * 4 + r];
            ssf[rl * MERGE_STRIDE + p] = s[ti * 4 + r];
        }
    __syncthreads();
    if (tid < TM) {
        float M = -INFINITY;
#pragma unroll
        for (int x = 0; x < 32; ++x) M = fmaxf(M, smf[tid * MERGE_STRIDE + x]);
        float S = 0.0f;
#pragma unroll
        for (int x = 0; x < 32; ++x)
            S += ssf[tid * MERGE_STRIDE + x]
               * __builtin_amdgcn_exp2f(smf[tid * MERGE_STRIDE + x] - M);
        // L2-bypassing stores so any XCD's group-finisher sees them.
        __hip_atomic_store(part_m + (size_t)(rowBase + tid) * NSLICE + slice, M,
                           __ATOMIC_RELAXED, __HIP_MEMORY_SCOPE_AGENT);
        __hip_atomic_store(part_s + (size_t)(rowBase + tid) * NSLICE + slice, S,
                           __ATOMIC_RELAXED, __HIP_MEMORY_SCOPE_AGENT);
    }
    __syncthreads();

    // Row-group finisher: last of this row-group's 16 blocks combines slices.
    if (tid == 0) {
        const unsigned o = __hip_atomic_fetch_add(
            grp + bx, 1u, __ATOMIC_ACQ_REL, __HIP_MEMORY_SCOPE_AGENT);
        sFlag = (o == NSLICE - 1);
    }
    __syncthreads();
    if (!sFlag) return;

    float* red = (float*)lds;              // reduction overlay
    float local = 0.0f;
    if (tid < TM) {
        const int row = rowBase + tid;
        if ((row & 255) != 255) {
            float pm[NSLICE], ps[NSLICE];
#pragma unroll
            for (int x = 0; x < NSLICE; ++x) {
                pm[x] = __hip_atomic_load(part_m + (size_t)row * NSLICE + x,
                                          __ATOMIC_RELAXED, __HIP_MEMORY_SCOPE_AGENT);
                ps[x] = __hip_atomic_load(part_s + (size_t)row * NSLICE + x,
                                          __ATOMIC_RELAXED, __HIP_MEMORY_SCOPE_AGENT);
            }
            float M = -INFINITY;
#pragma unroll
            for (int x = 0; x < NSLICE; ++x) M = fmaxf(M, pm[x]);
            float S = 0.0f;
#pragma unroll
            for (int x = 0; x < NSLICE; ++x)
                S += ps[x] * __builtin_amdgcn_exp2f(pm[x] - M);
            const float lse = LN2 * (M + __builtin_amdgcn_logf(S));
            const float pv  = __hip_atomic_load(pos + row, __ATOMIC_RELAXED,
                                                __HIP_MEMORY_SCOPE_AGENT);
            local = lse - pv;
        }
    }
    red[tid] = local;
    __syncthreads();
    for (int st = 128; st > 0; st >>= 1) {
        if (tid < st) red[tid] += red[tid + st];
        __syncthreads();
    }
    if (tid == 0) {
        atomicAdd(loss, red[0]);           // device-scope float atomic
        const unsigned od = __hip_atomic_fetch_add(
            done, 1u, __ATOMIC_ACQ_REL, __HIP_MEMORY_SCOPE_AGENT);
        if (od == NROWS / TM - 1) {
            const float total = __hip_atomic_load(loss, __ATOMIC_RELAXED,
                                                  __HIP_MEMORY_SCOPE_AGENT);
            out[0] = total / 4080.0f;      // B*(L-1) valid pairs
        }
    }
}

extern "C" void kernel_launch(void* const* d_in, const int* in_sizes, int n_in,
                              void* d_out, int out_size, void* d_ws, size_t ws_size,
                              hipStream_t stream) {
    const float* z   = (const float*)d_in[0];   // [4096, 256]
    // d_in[1] = va_values: dead code in the reference, unused.
    const float* mem = (const float*)d_in[2];   // [16384, 256]

    // ws layout: cand bf16 [20480*256] | part_m f32 [4096*16]
    //          | part_s f32 [4096*16] | pos f32 [4096] | ctrl u32 [64]
    ushort_t* cand = (ushort_t*)d_ws;
    float* part_m  = (float*)(cand + (size_t)NCAND * DIM);
    float* part_s  = part_m + (size_t)NROWS * NSLICE;
    float* pos     = part_s + (size_t)NROWS * NSLICE;
    unsigned* ctrl = (unsigned*)(pos + NROWS);

    const int castBlocks = NCAND * DIM / 4 / 256;   // 5120
    cast_kernel<<<dim3(castBlocks), dim3(256), 0, stream>>>(z, mem, cand, ctrl);
    mfma_lse_kernel<<<dim3(NROWS / TM, NSLICE), dim3(256), 0, stream>>>(
        cand, z, part_m, part_s, pos, ctrl, (float*)d_out);
}

// Round 7
// 143.672 us; speedup vs baseline: 1.4985x; 1.4985x over previous
//
#include <hip/hip_runtime.h>
#include <hip/hip_bf16.h>
#include <math.h>

// Problem constants (B=16, L=256, D=256, K=16384)
#define NROWS 4096               // B*L anchors / z rows
#define KMEM  16384
#define NCAND 20480              // NROWS + KMEM candidates
#define DIM   256                // feature dim
#define TM    128                // anchor rows per block
#define TN    128                // candidate cols per tile
#define BK    64                 // k-depth per LDS stage (bf16)
#define NSLICE 16                // 512 blocks = 2 blocks/CU (64KB LDS)
#define COLS_PER_SLICE (NCAND / NSLICE)       // 1280
#define TILES_PER_SLICE (COLS_PER_SLICE / TN) // 10
#define INV_T  (1.0f / 0.07f)
#define SCALE2 (1.4426950408889634f / 0.07f)  // log2(e)/T
#define LN2    0.6931471805599453f
#define MERGE_STRIDE 33          // conflict-free merge: (tid*33+x)%32 distinct

typedef short  short8 __attribute__((ext_vector_type(8)));  // 8 bf16 (4 VGPRs)
typedef float  f32x4  __attribute__((ext_vector_type(4)));  // MFMA C/D
typedef unsigned short ushort_t;

// RNE float->bf16 (inputs are finite normals; no NaN path needed)
__device__ inline ushort_t f2bf(float x) {
    union { float f; unsigned u; } a; a.f = x;
    unsigned r = a.u + 0x7fff + ((a.u >> 16) & 1);
    return (ushort_t)(r >> 16);
}

// async global->LDS, 16B per lane, dest = wave-uniform base + lane*16
__device__ inline void load_lds16(const void* g, void* l) {
    __builtin_amdgcn_global_load_lds(
        (const __attribute__((address_space(1))) unsigned int*)g,
        (__attribute__((address_space(3))) unsigned int*)l, 16, 0, 0);
}

// Kernel 0: cast fp32 -> bf16 into cand = [z ; mem]; zero control words
// (grp[32] row-group counters, done, loss). Kernel-boundary ordering makes
// the zeroed ctrl visible to the mfma kernel.
__global__ __launch_bounds__(256) void cast_kernel(
    const float* __restrict__ z, const float* __restrict__ mem,
    ushort_t* __restrict__ cand, unsigned* __restrict__ ctrl)
{
    if (blockIdx.x == 0 && threadIdx.x < 34) ctrl[threadIdx.x] = 0u;
    const int idx = blockIdx.x * 256 + threadIdx.x;  // float4 index, < 1310720
    const int ZQ = NROWS * DIM / 4;                  // 262144
    const float4 v = (idx < ZQ) ? ((const float4*)z)[idx]
                                : ((const float4*)mem)[idx - ZQ];
    ushort4 u; u.x = f2bf(v.x); u.y = f2bf(v.y); u.z = f2bf(v.z); u.w = f2bf(v.w);
    ((ushort4*)cand)[idx] = u;
}

// Kernel A: R5's proven double-buffered MFMA flash-LSE (verbatim main loop:
// 40-stage pipeline, prefetch into alternate buffer before compute, one
// barrier per stage) + fused finisher tail. The tail (32 of 512 blocks)
// computes fp32 pos-dots, combines slice partials, and accumulates the loss
// — no prologue work, no main-loop layout changes (R6's two regressions).
__global__ __launch_bounds__(256) void mfma_lse_kernel(
    const ushort_t* __restrict__ cand, const float* __restrict__ zf,
    float* __restrict__ part_m, float* __restrict__ part_s,
    unsigned* __restrict__ ctrl, float* __restrict__ out)
{
    __shared__ __align__(16) char smem_raw[65536];       // 2x(A 16KB + B 16KB)
    __shared__ int sFlag;
    ushort_t* ldsA = (ushort_t*)smem_raw;                // [2][128*64]
    ushort_t* ldsB = ldsA + 2 * TM * BK;                 // [2][128*64]

    const int tid  = threadIdx.x;
    const int lane = tid & 63;
    const int w    = tid >> 6;        // wave 0..3
    const int wr   = w >> 1;          // wave row half (0/1)
    const int wc   = w & 1;           // wave col half
    const int quad = lane >> 4;
    const int ln   = lane & 15;
    const int bx   = blockIdx.x;
    const int rowBase = bx * TM;
    const int slice   = blockIdx.y;
    const int colSliceBase = slice * COLS_PER_SLICE;

    unsigned* grp  = ctrl;            // [32] row-group arrival counters
    unsigned* done = ctrl + 32;       // group-finisher count
    float*    loss = (float*)(ctrl + 33);

    // Staging geometry (R5): wave w covers tile rows [w*32, w*32+32),
    // lane l -> row srow + u*8, chunk c = (l&7)^(srow&7). 8 rows x 128B
    // contiguous per instruction (coalesced); XOR swizzle keeps fragment
    // ds_read_b128 conflict-free.
    const int srow = w * 32 + (lane >> 3);
    const int sc   = (lane & 7) ^ (srow & 7);
    const ushort_t* agp    = cand + (size_t)(rowBase + srow) * DIM + sc * 8;
    const ushort_t* bgbase = cand + (size_t)(colSliceBase + srow) * DIM + sc * 8;
    ushort_t* lab = ldsA + (w * 32) * BK;   // + buf*TM*BK + u*8*BK
    ushort_t* lbb = ldsB + (w * 32) * BK;

    auto stage = [&](int t, int kk, int buf) {
        const ushort_t* ag = agp + kk;
        const ushort_t* bg = bgbase + t * (TN * DIM) + kk;
        ushort_t* la = lab + buf * (TM * BK);
        ushort_t* lb = lbb + buf * (TM * BK);
#pragma unroll
        for (int u = 0; u < 4; ++u) {
            load_lds16(ag + u * 8 * DIM, la + u * 8 * BK);
            load_lds16(bg + u * 8 * DIM, lb + u * 8 * BK);
        }
    };

    float m2[16], s[16];
#pragma unroll
    for (int i = 0; i < 16; ++i) { m2[i] = -INFINITY; s[i] = 0.0f; }

    f32x4 acc[4][4];
#pragma unroll
    for (int ti = 0; ti < 4; ++ti)
#pragma unroll
        for (int tj = 0; tj < 4; ++tj) acc[ti][tj] = (f32x4)0.0f;

    stage(0, 0, 0);        // prologue: stage 0 -> buffer 0
    __syncthreads();

    for (int t = 0; t < TILES_PER_SLICE; ++t) {
#pragma unroll
        for (int q = 0; q < 4; ++q) {
            const int buf = q & 1;          // s = 4t+q -> buf = s&1 = q&1
            if (q < 3)                        stage(t,     (q + 1) * BK, buf ^ 1);
            else if (t + 1 < TILES_PER_SLICE) stage(t + 1, 0,            buf ^ 1);

            const ushort_t* la = ldsA + buf * (TM * BK);
            const ushort_t* lb = ldsB + buf * (TM * BK);
#pragma unroll
            for (int ks = 0; ks < 2; ++ks) {
                short8 af[4], bfr[4];
#pragma unroll
                for (int ti = 0; ti < 4; ++ti) {
                    const int row = wr * 64 + ti * 16 + ln;
                    const int p = row * 8 + ((ks * 4 + quad) ^ (row & 7));
                    af[ti] = *(const short8*)(la + p * 8);
                }
#pragma unroll
                for (int tj = 0; tj < 4; ++tj) {
                    const int col = wc * 64 + tj * 16 + ln;
                    const int p = col * 8 + ((ks * 4 + quad) ^ (col & 7));
                    bfr[tj] = *(const short8*)(lb + p * 8);
                }
#pragma unroll
                for (int ti = 0; ti < 4; ++ti)
#pragma unroll
                    for (int tj = 0; tj < 4; ++tj)
                        acc[ti][tj] = __builtin_amdgcn_mfma_f32_16x16x32_bf16(
                            af[ti], bfr[tj], acc[ti][tj], 0, 0, 0);
            }

            if (q == 3) {
                // Per-tile epilogue (runs while next tile's loads fly).
                // C/D layout: col = ln+16*tj+64*wc, row = quad*4+reg+16*ti+64*wr
                const int colBase = colSliceBase + t * TN;
                const bool hasDiag =
                    (colBase < rowBase + TM) && (rowBase < colBase + TN);
#pragma unroll
                for (int ti = 0; ti < 4; ++ti) {
#pragma unroll
                    for (int r = 0; r < 4; ++r) {
                        const int idx = ti * 4 + r;
                        float v0 = acc[ti][0][r], v1 = acc[ti][1][r];
                        float v2 = acc[ti][2][r], v3 = acc[ti][3][r];
                        if (hasDiag) {
                            const int grow = rowBase + wr * 64 + ti * 16 + quad * 4 + r;
                            const int gc0  = colBase + wc * 64 + ln;
                            if (gc0      == grow) v0 = -3.0e38f;  // mask self
                            if (gc0 + 16 == grow) v1 = -3.0e38f;
                            if (gc0 + 32 == grow) v2 = -3.0e38f;
                            if (gc0 + 48 == grow) v3 = -3.0e38f;
                        }
                        const float tmax = fmaxf(fmaxf(v0, v1), fmaxf(v2, v3)) * SCALE2;
                        const float mo = m2[idx];
                        const float mn = fmaxf(mo, tmax);
                        const float sc2 = __builtin_amdgcn_exp2f(mo - mn);
                        s[idx] = s[idx] * sc2
                               + __builtin_amdgcn_exp2f(fmaf(v0, SCALE2, -mn))
                               + __builtin_amdgcn_exp2f(fmaf(v1, SCALE2, -mn))
                               + __builtin_amdgcn_exp2f(fmaf(v2, SCALE2, -mn))
                               + __builtin_amdgcn_exp2f(fmaf(v3, SCALE2, -mn));
                        m2[idx] = mn;
                        acc[ti][0][r] = 0.0f; acc[ti][1][r] = 0.0f;
                        acc[ti][2][r] = 0.0f; acc[ti][3][r] = 0.0f;
                    }
                }
            }
            __syncthreads();   // publishes prefetched stage; frees old buffer
        }
    }

    // Cross-lane merge: 32 partials per row (16 ln x 2 wc), stride-33 overlay.
    float* smf = (float*)smem_raw;         // [128][33] m partials
    float* ssf = smf + TM * MERGE_STRIDE;  // [128][33] s partials
    const int p = wc * 16 + ln;
#pragma unroll
    for (int ti = 0; ti < 4; ++ti)
#pragma unroll
        for (int r = 0; r < 4; ++r) {
            const int rl = wr * 64 + ti * 16 + quad * 4 + r;
            smf[rl * MERGE_STRIDE + p] = m2[ti * 4 + r];
            ssf[rl * MERGE_STRIDE + p] = s[ti * 4 + r];
        }
    __syncthreads();
    if (tid < TM) {
        float M = -INFINITY;
#pragma unroll
        for (int x = 0; x < 32; ++x) M = fmaxf(M, smf[tid * MERGE_STRIDE + x]);
        float S = 0.0f;
#pragma unroll
        for (int x = 0; x < 32; ++x)
            S += ssf[tid * MERGE_STRIDE + x]
               * __builtin_amdgcn_exp2f(smf[tid * MERGE_STRIDE + x] - M);
        // Agent-scope stores so any XCD's group-finisher sees them.
        __hip_atomic_store(part_m + (size_t)(rowBase + tid) * NSLICE + slice, M,
                           __ATOMIC_RELAXED, __HIP_MEMORY_SCOPE_AGENT);
        __hip_atomic_store(part_s + (size_t)(rowBase + tid) * NSLICE + slice, S,
                           __ATOMIC_RELAXED, __HIP_MEMORY_SCOPE_AGENT);
    }
    __syncthreads();

    // Row-group finisher: last of this row-group's 16 blocks combines slices,
    // computes fp32 pos-dots (2 threads/row), accumulates the loss.
    if (tid == 0) {
        const unsigned o = __hip_atomic_fetch_add(
            grp + bx, 1u, __ATOMIC_ACQ_REL, __HIP_MEMORY_SCOPE_AGENT);
        sFlag = (o == NSLICE - 1);
    }
    __syncthreads();
    if (!sFlag) return;

    float* dhalf = (float*)smem_raw;       // [256] half-dots
    float* red   = dhalf + 256;            // [256] reduction
    const int row  = rowBase + (tid >> 1);
    const int half = tid & 1;
    float dotp = 0.0f;
    if ((row & 255) != 255) {              // valid pair; also guards row 4095
        const float4* a = (const float4*)(zf + (size_t)row * DIM + half * 128);
        const float4* b = (const float4*)(zf + (size_t)(row + 1) * DIM + half * 128);
#pragma unroll 4
        for (int qq = 0; qq < 32; ++qq) {
            const float4 av = a[qq], bv = b[qq];
            dotp += av.x * bv.x + av.y * bv.y + av.z * bv.z + av.w * bv.w;
        }
    }
    dhalf[tid] = dotp;
    __syncthreads();
    float local = 0.0f;
    if (half == 0 && (row & 255) != 255) {
        const float dot = dhalf[tid] + dhalf[tid + 1];
        float M = -INFINITY, S = 0.0f;
        float pm[NSLICE], ps[NSLICE];
#pragma unroll
        for (int x = 0; x < NSLICE; ++x) {
            pm[x] = __hip_atomic_load(part_m + (size_t)row * NSLICE + x,
                                      __ATOMIC_RELAXED, __HIP_MEMORY_SCOPE_AGENT);
            ps[x] = __hip_atomic_load(part_s + (size_t)row * NSLICE + x,
                                      __ATOMIC_RELAXED, __HIP_MEMORY_SCOPE_AGENT);
        }
#pragma unroll
        for (int x = 0; x < NSLICE; ++x) M = fmaxf(M, pm[x]);
#pragma unroll
        for (int x = 0; x < NSLICE; ++x)
            S += ps[x] * __builtin_amdgcn_exp2f(pm[x] - M);
        const float lse = LN2 * (M + __builtin_amdgcn_logf(S));
        local = lse - dot * INV_T;
    }
    red[tid] = local;
    __syncthreads();
    for (int st = 128; st > 0; st >>= 1) {
        if (tid < st) red[tid] += red[tid + st];
        __syncthreads();
    }
    if (tid == 0) {
        atomicAdd(loss, red[0]);           // device-scope float atomic
        const unsigned od = __hip_atomic_fetch_add(
            done, 1u, __ATOMIC_ACQ_REL, __HIP_MEMORY_SCOPE_AGENT);
        if (od == NROWS / TM - 1) {
            const float total = __hip_atomic_load(loss, __ATOMIC_RELAXED,
                                                  __HIP_MEMORY_SCOPE_AGENT);
            out[0] = total / 4080.0f;      // B*(L-1) valid pairs
        }
    }
}

extern "C" void kernel_launch(void* const* d_in, const int* in_sizes, int n_in,
                              void* d_out, int out_size, void* d_ws, size_t ws_size,
                              hipStream_t stream) {
    const float* z   = (const float*)d_in[0];   // [4096, 256]
    // d_in[1] = va_values: dead code in the reference, unused.
    const float* mem = (const float*)d_in[2];   // [16384, 256]

    // ws layout: cand bf16 [20480*256] | part_m f32 [4096*16]
    //          | part_s f32 [4096*16] | ctrl u32 [64]
    ushort_t* cand = (ushort_t*)d_ws;
    float* part_m  = (float*)(cand + (size_t)NCAND * DIM);
    float* part_s  = part_m + (size_t)NROWS * NSLICE;
    unsigned* ctrl = (unsigned*)(part_s + (size_t)NROWS * NSLICE);

    const int castBlocks = NCAND * DIM / 4 / 256;   // 5120
    cast_kernel<<<dim3(castBlocks), dim3(256), 0, stream>>>(z, mem, cand, ctrl);
    mfma_lse_kernel<<<dim3(NROWS / TM, NSLICE), dim3(256), 0, stream>>>(
        cand, z, part_m, part_s, ctrl, (float*)d_out);
}